// Round 8
// baseline (190.368 us; speedup 1.0000x reference)
//
#include <hip/hip_runtime.h>
#include <hip/hip_bf16.h>

#define HW_ 69696
#define W_ 264
#define H_ 264

typedef short bf16x8 __attribute__((ext_vector_type(8)));
typedef float f32x4 __attribute__((ext_vector_type(4)));

static __device__ __forceinline__ unsigned short f2b(float f) {
  __hip_bfloat16 h = __float2bfloat16(f);
  return *reinterpret_cast<unsigned short*>(&h);
}
static __device__ __forceinline__ float b2f(unsigned short u) {
  __hip_bfloat16 h;
  *reinterpret_cast<unsigned short*>(&h) = u;
  return __bfloat162float(h);
}
static __device__ __forceinline__ float lo_f(unsigned int u) {
  union { unsigned int i; float f; } c; c.i = u << 16; return c.f;
}
static __device__ __forceinline__ float hi_f(unsigned int u) {
  union { unsigned int i; float f; } c; c.i = u & 0xffff0000u; return c.f;
}

// ---------------- k_gemm: qkv = W(288x96) @ roll(x), fused pre, MFMA bf16, plane-8 out ----------------
__global__ __launch_bounds__(256, 3) void k_gemm(const float* __restrict__ x,
                                                 const float* __restrict__ w,
                                                 unsigned short* __restrict__ outb) {
  __shared__ __align__(16) char smem[46592];
  __shared__ int rp[128];
  unsigned short* As = (unsigned short*)smem;   // [96][104]
  unsigned short* Bs = As + 96 * 104;           // [128][104]

  const int tid = threadIdx.x;
  const int px0 = blockIdx.x * 128;
  const int oc = blockIdx.y;

  if (tid < 128) {
    int p = px0 + tid;
    int r = 0;
    if (p < HW_) {
      int y = p / W_, xx = p - y * W_;
      int y2 = y + 4; if (y2 >= H_) y2 -= H_;
      int x2 = xx + 4; if (x2 >= W_) x2 -= W_;
      r = y2 * W_ + x2;
    }
    rp[tid] = r;
  }

  const float* wp = w + oc * 96 * 96;
  for (int l = tid; l < 96 * 24; l += 256) {
    int o = l / 24, c4 = (l - (l / 24) * 24) * 4;
    float4 v = *(const float4*)&wp[o * 96 + c4];
    unsigned int p0 = (unsigned int)f2b(v.x) | ((unsigned int)f2b(v.y) << 16);
    unsigned int p1 = (unsigned int)f2b(v.z) | ((unsigned int)f2b(v.w) << 16);
    *(uint2*)&As[o * 104 + c4] = make_uint2(p0, p1);
  }
  __syncthreads();

  for (int l = tid; l < 128 * 12; l += 256) {
    int pxl = l & 127, g = l >> 7;
    uint4 o = make_uint4(0u, 0u, 0u, 0u);
    if (px0 + pxl < HW_) {
      const int base = rp[pxl];
      const float* xp = x + (size_t)(g * 8) * HW_ + base;
      float f0 = xp[0];
      float f1 = xp[HW_];
      float f2 = xp[2 * HW_];
      float f3 = xp[3 * HW_];
      float f4 = xp[4 * HW_];
      float f5 = xp[5 * HW_];
      float f6 = xp[6 * HW_];
      float f7 = xp[7 * HW_];
      o.x = (unsigned int)f2b(f0) | ((unsigned int)f2b(f1) << 16);
      o.y = (unsigned int)f2b(f2) | ((unsigned int)f2b(f3) << 16);
      o.z = (unsigned int)f2b(f4) | ((unsigned int)f2b(f5) << 16);
      o.w = (unsigned int)f2b(f6) | ((unsigned int)f2b(f7) << 16);
    }
    *(uint4*)&Bs[pxl * 104 + g * 8] = o;
  }
  __syncthreads();

  const int wid = tid >> 6, lane = tid & 63;
  const int quad = lane >> 4, lo = lane & 15;
  f32x4 acc[6][2];
#pragma unroll
  for (int mt = 0; mt < 6; ++mt)
#pragma unroll
    for (int nt = 0; nt < 2; ++nt) acc[mt][nt] = {0.f, 0.f, 0.f, 0.f};

#pragma unroll
  for (int ks = 0; ks < 3; ++ks) {
    const int kb = ks * 32 + quad * 8;
    bf16x8 b[2];
#pragma unroll
    for (int nt = 0; nt < 2; ++nt)
      b[nt] = *(const bf16x8*)&Bs[(wid * 32 + nt * 16 + lo) * 104 + kb];
#pragma unroll
    for (int mt = 0; mt < 6; ++mt) {
      bf16x8 a = *(const bf16x8*)&As[(mt * 16 + lo) * 104 + kb];
#pragma unroll
      for (int nt = 0; nt < 2; ++nt)
        acc[mt][nt] = __builtin_amdgcn_mfma_f32_16x16x32_bf16(a, b[nt], acc[mt][nt], 0, 0, 0);
    }
  }

  __syncthreads();
  unsigned short* Cs2 = (unsigned short*)smem;  // [128][104] px-major overlay
#pragma unroll
  for (int mt = 0; mt < 6; ++mt)
#pragma unroll
    for (int nt = 0; nt < 2; ++nt) {
      int px_l = wid * 32 + nt * 16 + lo;
#pragma unroll
      for (int r = 0; r < 4; ++r)
        Cs2[px_l * 104 + mt * 16 + quad * 4 + r] = f2b(acc[mt][nt][r]);
    }
  __syncthreads();
  for (int i = tid; i < 128 * 12; i += 256) {
    int pxl = i & 127, j = i >> 7;
    if (px0 + pxl < HW_)
      *((uint4*)outb + (size_t)(oc * 12 + j) * HW_ + px0 + pxl) =
          ((const uint4*)(Cs2 + pxl * 104))[j];
  }
}

// ---------------- k_dwattn: fused 3x3 depthwise conv + MFMA windowed channel attention ----------------
// block = (window wi, tile t), 192 thr = 3 waves, wave h = head h.
// qkv: plane-8 [36][HW][8] bf16 (pre-dw). tout: [t][4096][96] bf16 records.
#define FP1 200  // shorts per px in flat (q 0..95, k 96..191, pad)
__global__ __launch_bounds__(192) void k_dwattn(const unsigned short* __restrict__ qkv,
                                                const float* __restrict__ dw,
                                                const float* __restrict__ temp,
                                                unsigned short* __restrict__ tout) {
  // layout: [0,20160) sIn uint4[12][105] (attnL ushort[96][40] overlays after convs)
  //         [20160,45760) flat ushort[64][200]  (Cs ushort[64][104] overlays in epilogue)
  //         [45760,59072) vS ushort[64][104]
  //         [59072,59456) invn float[96]
  __shared__ __align__(16) char smem[59456];
  uint4* sIn = (uint4*)smem;
  unsigned short* flat = (unsigned short*)(smem + 20160);
  unsigned short* vS = (unsigned short*)(smem + 45760);
  float* invn = (float*)(smem + 59072);
  unsigned short* attnL = (unsigned short*)smem;
  unsigned short* Cs = flat;

  const int tid = threadIdx.x;
  const int wi = blockIdx.x, t = blockIdx.y;
  const int i0 = (t / 5) * 50, j0 = (t % 5) * 50;
  const int wy = wi >> 3, wx = wi & 7;
  const int gy0 = i0 + wy * 8, gx0 = j0 + wx * 8;

  const int cuu = tid >> 4;  // 0..11: plane-in-chunk
  const int cs = tid & 15;

  // ---- fused depthwise conv: 3 chunks (q, k, v), each 12 planes ----
#pragma unroll
  for (int c3 = 0; c3 < 3; ++c3) {
    for (int idx = tid; idx < 1200; idx += 192) {
      int uu = idx / 100, p = idx - uu * 100;
      int r = p / 10, j = p - r * 10;
      int gy = gy0 - 1 + r, gx = gx0 - 1 + j;
      uint4 v = make_uint4(0u, 0u, 0u, 0u);
      if ((unsigned)gy < (unsigned)H_ && (unsigned)gx < (unsigned)W_)
        v = ((const uint4*)qkv)[(size_t)(c3 * 12 + uu) * HW_ + gy * W_ + gx];
      sIn[uu * 105 + p] = v;
    }
    float wv[72];
    {
      const float* wp = dw + (c3 * 12 + cuu) * 72;
#pragma unroll
      for (int i = 0; i < 72; ++i) wv[i] = wp[i];
    }
    __syncthreads();
#pragma unroll
    for (int k = 0; k < 4; ++k) {
      const int px = cs + k * 16;
      const int r = px >> 3, j = px & 7;
      float acc[8] = {0.f, 0.f, 0.f, 0.f, 0.f, 0.f, 0.f, 0.f};
#pragma unroll
      for (int dy = 0; dy < 3; ++dy)
#pragma unroll
        for (int dx = 0; dx < 3; ++dx) {
          uint4 v = sIn[cuu * 105 + (r + dy) * 10 + (j + dx)];
          const int tp = dy * 3 + dx;
          acc[0] += wv[0 * 9 + tp] * lo_f(v.x); acc[1] += wv[1 * 9 + tp] * hi_f(v.x);
          acc[2] += wv[2 * 9 + tp] * lo_f(v.y); acc[3] += wv[3 * 9 + tp] * hi_f(v.y);
          acc[4] += wv[4 * 9 + tp] * lo_f(v.z); acc[5] += wv[5 * 9 + tp] * hi_f(v.z);
          acc[6] += wv[6 * 9 + tp] * lo_f(v.w); acc[7] += wv[7 * 9 + tp] * hi_f(v.w);
        }
      uint4 o;
      o.x = (unsigned int)f2b(acc[0]) | ((unsigned int)f2b(acc[1]) << 16);
      o.y = (unsigned int)f2b(acc[2]) | ((unsigned int)f2b(acc[3]) << 16);
      o.z = (unsigned int)f2b(acc[4]) | ((unsigned int)f2b(acc[5]) << 16);
      o.w = (unsigned int)f2b(acc[6]) | ((unsigned int)f2b(acc[7]) << 16);
      if (c3 == 0) *(uint4*)&flat[px * FP1 + cuu * 8] = o;
      else if (c3 == 1) *(uint4*)&flat[px * FP1 + 96 + cuu * 8] = o;
      else *(uint4*)&vS[px * 104 + cuu * 8] = o;
    }
    __syncthreads();
  }

  // ---- attention ----
  const int h = tid >> 6, lane = tid & 63;
  const int quad = lane >> 4, lo = lane & 15;
  const int cb = h * 32;

  bf16x8 qf[2][2], kf[2][2];
#pragma unroll
  for (int mt = 0; mt < 2; ++mt)
#pragma unroll
    for (int kt = 0; kt < 2; ++kt) {
      const int rbase = ((kt * 4 + quad) * 8) * FP1;
      const int cq = cb + mt * 16 + lo;
      const int ck = 96 + cb + mt * 16 + lo;
      bf16x8 q8, k8;
#pragma unroll
      for (int j = 0; j < 8; ++j) {
        q8[j] = (short)flat[rbase + j * FP1 + cq];
        k8[j] = (short)flat[rbase + j * FP1 + ck];
      }
      qf[mt][kt] = q8;
      kf[mt][kt] = k8;
    }

  f32x4 S[2][2];
#pragma unroll
  for (int mt = 0; mt < 2; ++mt)
#pragma unroll
    for (int nt = 0; nt < 2; ++nt) {
      S[mt][nt] = {0.f, 0.f, 0.f, 0.f};
#pragma unroll
      for (int kt = 0; kt < 2; ++kt)
        S[mt][nt] = __builtin_amdgcn_mfma_f32_16x16x32_bf16(qf[mt][kt], kf[nt][kt], S[mt][nt], 0, 0, 0);
    }

  float ivk[2];
#pragma unroll
  for (int mt = 0; mt < 2; ++mt) {
    float sq = 0.f, sk = 0.f;
#pragma unroll
    for (int kt = 0; kt < 2; ++kt)
#pragma unroll
      for (int j = 0; j < 8; ++j) {
        float a = b2f((unsigned short)qf[mt][kt][j]);
        float b = b2f((unsigned short)kf[mt][kt][j]);
        sq += a * a;
        sk += b * b;
      }
    sq += __shfl_xor(sq, 16);
    sq += __shfl_xor(sq, 32);
    sk += __shfl_xor(sk, 16);
    sk += __shfl_xor(sk, 32);
    if (quad == 0) invn[h * 32 + mt * 16 + lo] = 1.f / fmaxf(sqrtf(sq), 1e-12f);
    ivk[mt] = 1.f / fmaxf(sqrtf(sk), 1e-12f);
  }
  __syncthreads();

  const float ts = temp[h];
#pragma unroll
  for (int mt = 0; mt < 2; ++mt)
#pragma unroll
    for (int nt = 0; nt < 2; ++nt)
#pragma unroll
      for (int r = 0; r < 4; ++r) {
        int c = mt * 16 + quad * 4 + r;
        float v = S[mt][nt][r] * invn[h * 32 + c] * ivk[nt] * ts;
        attnL[(h * 32 + c) * 40 + nt * 16 + lo] = f2b(fmaxf(v, 0.f));
      }
  __syncthreads();

  bf16x8 af[2];
#pragma unroll
  for (int mt = 0; mt < 2; ++mt)
    af[mt] = *(const bf16x8*)&attnL[(h * 32 + mt * 16 + lo) * 40 + quad * 8];

  f32x4 O[2][4];
#pragma unroll
  for (int nt = 0; nt < 4; ++nt) {
    const int px = nt * 16 + lo;
    bf16x8 vf = *(const bf16x8*)&vS[px * 104 + cb + quad * 8];
#pragma unroll
    for (int mt = 0; mt < 2; ++mt) {
      f32x4 z = {0.f, 0.f, 0.f, 0.f};
      O[mt][nt] = __builtin_amdgcn_mfma_f32_16x16x32_bf16(af[mt], vf, z, 0, 0, 0);
    }
  }
  __syncthreads();  // all flat/vS/attnL reads complete before overlay

  // transpose O -> px-major records in LDS (overlay flat), coalesced store
#pragma unroll
  for (int mt = 0; mt < 2; ++mt)
#pragma unroll
    for (int nt = 0; nt < 4; ++nt) {
      const int px = nt * 16 + lo;
      unsigned int p0 = (unsigned int)f2b(O[mt][nt][0]) | ((unsigned int)f2b(O[mt][nt][1]) << 16);
      unsigned int p1 = (unsigned int)f2b(O[mt][nt][2]) | ((unsigned int)f2b(O[mt][nt][3]) << 16);
      *(uint2*)&Cs[px * 104 + cb + mt * 16 + quad * 4] = make_uint2(p0, p1);
    }
  __syncthreads();

  for (int idx = tid; idx < 64 * 12; idx += 192) {
    int rec = idx / 12, u = idx - (idx / 12) * 12;
    int r = rec >> 3, j = rec & 7;
    size_t g = (size_t)t * 4096 + (wy * 8 + r) * 64 + wx * 8 + j;
    ((uint4*)tout)[g * 12 + u] = ((const uint4*)(Cs + rec * 104))[u];
  }
}

// ---------------- k_avgproj: overlap-average + 1x1 proj + roll(+4,+4), f32 out ----------------
__global__ __launch_bounds__(256, 4) void k_avgproj(const float* __restrict__ w,
                                                    const unsigned short* __restrict__ tout,
                                                    float* __restrict__ outf) {
  __shared__ __align__(16) char smem[33280];
  unsigned short* As = (unsigned short*)smem;   // [96][104]
  unsigned short* Bs = As + 96 * 104;           // [64][104]

  const int tid = threadIdx.x;
  const int px0 = blockIdx.x * 64;

  for (int l = tid; l < 96 * 24; l += 256) {
    int o = l / 24, c4 = (l - (l / 24) * 24) * 4;
    float4 v = *(const float4*)&w[o * 96 + c4];
    unsigned int p0 = (unsigned int)f2b(v.x) | ((unsigned int)f2b(v.y) << 16);
    unsigned int p1 = (unsigned int)f2b(v.z) | ((unsigned int)f2b(v.w) << 16);
    *(uint2*)&As[o * 104 + c4] = make_uint2(p0, p1);
  }

  {
    const int pxl = tid >> 2, q = tid & 3;
    const int px = px0 + pxl;
    unsigned short* bd = Bs + pxl * 104 + q * 24;
    const int y = px / W_, xx = px - y * W_;
    int loy = (y >= 64) ? (y - 14) / 50 : 0;
    int hiy = y / 50; if (hiy > 4) hiy = 4;
    int lox = (xx >= 64) ? (xx - 14) / 50 : 0;
    int hix = xx / 50; if (hix > 4) hix = 4;
    float acc[24];
#pragma unroll
    for (int i = 0; i < 24; ++i) acc[i] = 0.f;
    int cnt = 0;
    for (int ty = loy; ty <= hiy; ++ty)
      for (int tx = lox; tx <= hix; ++tx) {
        size_t rec = (size_t)(ty * 5 + tx) * 4096 + ((y - ty * 50) << 6) + (xx - tx * 50);
        const uint4* rp = (const uint4*)tout + rec * 12 + q * 3;
#pragma unroll
        for (int ui = 0; ui < 3; ++ui) {
          uint4 v = rp[ui];
          acc[ui * 8 + 0] += lo_f(v.x); acc[ui * 8 + 1] += hi_f(v.x);
          acc[ui * 8 + 2] += lo_f(v.y); acc[ui * 8 + 3] += hi_f(v.y);
          acc[ui * 8 + 4] += lo_f(v.z); acc[ui * 8 + 5] += hi_f(v.z);
          acc[ui * 8 + 6] += lo_f(v.w); acc[ui * 8 + 7] += hi_f(v.w);
        }
        ++cnt;
      }
    const float inv = 1.f / (float)cnt;
#pragma unroll
    for (int ui = 0; ui < 3; ++ui) {
      uint4 o;
      o.x = (unsigned int)f2b(acc[ui * 8 + 0] * inv) | ((unsigned int)f2b(acc[ui * 8 + 1] * inv) << 16);
      o.y = (unsigned int)f2b(acc[ui * 8 + 2] * inv) | ((unsigned int)f2b(acc[ui * 8 + 3] * inv) << 16);
      o.z = (unsigned int)f2b(acc[ui * 8 + 4] * inv) | ((unsigned int)f2b(acc[ui * 8 + 5] * inv) << 16);
      o.w = (unsigned int)f2b(acc[ui * 8 + 6] * inv) | ((unsigned int)f2b(acc[ui * 8 + 7] * inv) << 16);
      ((uint4*)bd)[ui] = o;
    }
  }
  __syncthreads();

  const int wid = tid >> 6, lane = tid & 63;
  const int quad = lane >> 4, lo = lane & 15;
  f32x4 acc[6];
#pragma unroll
  for (int mt = 0; mt < 6; ++mt) acc[mt] = {0.f, 0.f, 0.f, 0.f};

#pragma unroll
  for (int ks = 0; ks < 3; ++ks) {
    const int kb = ks * 32 + quad * 8;
    bf16x8 b = *(const bf16x8*)&Bs[(wid * 16 + lo) * 104 + kb];
#pragma unroll
    for (int mt = 0; mt < 6; ++mt) {
      bf16x8 a = *(const bf16x8*)&As[(mt * 16 + lo) * 104 + kb];
      acc[mt] = __builtin_amdgcn_mfma_f32_16x16x32_bf16(a, b, acc[mt], 0, 0, 0);
    }
  }

  {
    int px = px0 + wid * 16 + lo;
    int y = px / W_, xx = px - y * W_;
    int y2 = y + 4; if (y2 >= H_) y2 -= H_;
    int x2 = xx + 4; if (x2 >= W_) x2 -= W_;
    int tp = y2 * W_ + x2;
#pragma unroll
    for (int mt = 0; mt < 6; ++mt) {
      int row = mt * 16 + quad * 4;
#pragma unroll
      for (int r = 0; r < 4; ++r)
        outf[(size_t)(row + r) * HW_ + tp] = acc[mt][r];
    }
  }
}

extern "C" void kernel_launch(void* const* d_in, const int* in_sizes, int n_in,
                              void* d_out, int out_size, void* d_ws, size_t ws_size,
                              hipStream_t stream) {
  (void)in_sizes; (void)n_in; (void)out_size; (void)ws_size;
  const float* x = (const float*)d_in[0];
  const float* temp = (const float*)d_in[1];
  const float* qkvw = (const float*)d_in[2];
  const float* dww = (const float*)d_in[3];
  const float* projw = (const float*)d_in[4];
  float* out = (float*)d_out;

  char* ws = (char*)d_ws;
  const size_t SZQ = (size_t)288 * HW_ * 2;  // 40,144,896 B
  // [0, SZQ):      qkvb planes (read by k_dwattn)
  // [SZQ, ...):    tout records (19.7 MB)
  unsigned short* qkvb = (unsigned short*)ws;
  unsigned short* tout = (unsigned short*)(ws + SZQ);

  k_gemm<<<dim3(545, 3), 256, 0, stream>>>(x, qkvw, qkvb);
  k_dwattn<<<dim3(64, 25), 192, 0, stream>>>(qkvb, dww, temp, tout);
  k_avgproj<<<dim3(1089), 256, 0, stream>>>(projw, tout, out);
}

// Round 9
// 149.906 us; speedup vs baseline: 1.2699x; 1.2699x over previous
//
#include <hip/hip_runtime.h>
#include <hip/hip_bf16.h>

#define HW_ 69696
#define W_ 264
#define H_ 264

typedef short bf16x8 __attribute__((ext_vector_type(8)));
typedef float f32x4 __attribute__((ext_vector_type(4)));

static __device__ __forceinline__ unsigned short f2b(float f) {
  __hip_bfloat16 h = __float2bfloat16(f);
  return *reinterpret_cast<unsigned short*>(&h);
}
static __device__ __forceinline__ float b2f(unsigned short u) {
  __hip_bfloat16 h;
  *reinterpret_cast<unsigned short*>(&h) = u;
  return __bfloat162float(h);
}
static __device__ __forceinline__ float lo_f(unsigned int u) {
  union { unsigned int i; float f; } c; c.i = u << 16; return c.f;
}
static __device__ __forceinline__ float hi_f(unsigned int u) {
  union { unsigned int i; float f; } c; c.i = u & 0xffff0000u; return c.f;
}

// ---------------- k_gemm v2: qkv = W(288x96) @ roll(x), B in registers, 3 oc in-block ----------------
// grid 1089 x 64 px. LDS = A-tile only (Cs epilogue overlays it). plane-8 out.
__global__ __launch_bounds__(256, 4) void k_gemm(const float* __restrict__ x,
                                                 const float* __restrict__ w,
                                                 unsigned short* __restrict__ outb) {
  __shared__ __align__(16) char smem[19968];
  unsigned short* As = (unsigned short*)smem;   // [96][104]
  unsigned short* Cs = (unsigned short*)smem;   // [64][104] overlay (epilogue)

  const int tid = threadIdx.x;
  const int wid = tid >> 6, lane = tid & 63;
  const int quad = lane >> 4, lo = lane & 15;
  const int px0 = blockIdx.x * 64;
  const int px = px0 + wid * 16 + lo;   // always < HW_ (1089*64 == HW_)

  // roll(-4,-4) base for this lane's pixel
  const int y = px / W_, xx = px - y * W_;
  int y2 = y + 4; if (y2 >= H_) y2 -= H_;
  int x2 = xx + 4; if (x2 >= W_) x2 -= W_;
  const float* xb = x + y2 * W_ + x2;

  // B fragments direct from x: ch = ks*32 + quad*8 + i
  bf16x8 bf[3];
#pragma unroll
  for (int ks = 0; ks < 3; ++ks) {
    const float* xp = xb + (size_t)(ks * 32 + quad * 8) * HW_;
    float f[8];
#pragma unroll
    for (int i = 0; i < 8; ++i) f[i] = xp[(size_t)i * HW_];
    union { bf16x8 v; unsigned short s[8]; } u;
#pragma unroll
    for (int i = 0; i < 8; ++i) u.s[i] = f2b(f[i]);
    bf[ks] = u.v;
  }

  for (int oc = 0; oc < 3; ++oc) {
    __syncthreads();  // previous iteration's Cs reads done before re-staging A
    const float* wp = w + oc * 96 * 96;
    for (int l = tid; l < 96 * 24; l += 256) {
      int o = l / 24, c4 = (l - (l / 24) * 24) * 4;
      float4 v = *(const float4*)&wp[o * 96 + c4];
      unsigned int p0 = (unsigned int)f2b(v.x) | ((unsigned int)f2b(v.y) << 16);
      unsigned int p1 = (unsigned int)f2b(v.z) | ((unsigned int)f2b(v.w) << 16);
      *(uint2*)&As[o * 104 + c4] = make_uint2(p0, p1);
    }
    __syncthreads();

    f32x4 acc[6];
#pragma unroll
    for (int mt = 0; mt < 6; ++mt) acc[mt] = {0.f, 0.f, 0.f, 0.f};
#pragma unroll
    for (int ks = 0; ks < 3; ++ks) {
      const int kb = ks * 32 + quad * 8;
#pragma unroll
      for (int mt = 0; mt < 6; ++mt) {
        bf16x8 a = *(const bf16x8*)&As[(mt * 16 + lo) * 104 + kb];
        acc[mt] = __builtin_amdgcn_mfma_f32_16x16x32_bf16(a, bf[ks], acc[mt], 0, 0, 0);
      }
    }
    __syncthreads();  // A reads done before Cs overlay

    const int pxl = wid * 16 + lo;
#pragma unroll
    for (int mt = 0; mt < 6; ++mt) {
      unsigned int p0 = (unsigned int)f2b(acc[mt][0]) | ((unsigned int)f2b(acc[mt][1]) << 16);
      unsigned int p1 = (unsigned int)f2b(acc[mt][2]) | ((unsigned int)f2b(acc[mt][3]) << 16);
      *(uint2*)&Cs[pxl * 104 + mt * 16 + quad * 4] = make_uint2(p0, p1);
    }
    __syncthreads();

    for (int i = tid; i < 64 * 12; i += 256) {
      int pxl2 = i & 63, j = i >> 6;
      *((uint4*)outb + (size_t)(oc * 12 + j) * HW_ + px0 + pxl2) =
          ((const uint4*)(Cs + pxl2 * 104))[j];
    }
  }
}

// ---------------- k_dw: 3x3 depthwise conv, 2D-tiled LDS, plane-8 layout [36][HW][8] ----------------
__global__ __launch_bounds__(256) void k_dw(const unsigned short* __restrict__ qkv,
                                            const float* __restrict__ dw,
                                            unsigned short* __restrict__ out) {
  __shared__ __align__(16) uint4 inS[18 * 66];
  const int tid = threadIdx.x;
  const int x0 = blockIdx.x * 64;
  const int y0 = blockIdx.y * 16;
  const int u = blockIdx.z;  // 0..35
  const uint4* plane = (const uint4*)qkv + (size_t)u * HW_;
  const float* wp = dw + u * 72;
  float wv[72];
#pragma unroll
  for (int i = 0; i < 72; ++i) wv[i] = wp[i];

  for (int idx = tid; idx < 18 * 66; idx += 256) {
    int rr = idx / 66, cc = idx - rr * 66;
    int gy = y0 - 1 + rr, gx = x0 - 1 + cc;
    uint4 v = make_uint4(0u, 0u, 0u, 0u);
    if ((unsigned)gy < (unsigned)H_ && (unsigned)gx < (unsigned)W_)
      v = plane[gy * W_ + gx];
    inS[idx] = v;
  }
  __syncthreads();

#pragma unroll
  for (int k = 0; k < 4; ++k) {
    const int oidx = k * 256 + tid;
    const int ro = oidx >> 6, co = oidx & 63;
    const int y = y0 + ro, x = x0 + co;
    float acc[8] = {0.f, 0.f, 0.f, 0.f, 0.f, 0.f, 0.f, 0.f};
#pragma unroll
    for (int dy = 0; dy < 3; ++dy)
#pragma unroll
      for (int dx = 0; dx < 3; ++dx) {
        uint4 v = inS[(ro + dy) * 66 + co + dx];
        float w0 = wv[0 * 9 + dy * 3 + dx], w1 = wv[1 * 9 + dy * 3 + dx];
        float w2 = wv[2 * 9 + dy * 3 + dx], w3 = wv[3 * 9 + dy * 3 + dx];
        float w4 = wv[4 * 9 + dy * 3 + dx], w5 = wv[5 * 9 + dy * 3 + dx];
        float w6 = wv[6 * 9 + dy * 3 + dx], w7 = wv[7 * 9 + dy * 3 + dx];
        acc[0] += w0 * lo_f(v.x); acc[1] += w1 * hi_f(v.x);
        acc[2] += w2 * lo_f(v.y); acc[3] += w3 * hi_f(v.y);
        acc[4] += w4 * lo_f(v.z); acc[5] += w5 * hi_f(v.z);
        acc[6] += w6 * lo_f(v.w); acc[7] += w7 * hi_f(v.w);
      }
    if (y < H_ && x < W_) {
      uint4 o;
      o.x = (unsigned int)f2b(acc[0]) | ((unsigned int)f2b(acc[1]) << 16);
      o.y = (unsigned int)f2b(acc[2]) | ((unsigned int)f2b(acc[3]) << 16);
      o.z = (unsigned int)f2b(acc[4]) | ((unsigned int)f2b(acc[5]) << 16);
      o.w = (unsigned int)f2b(acc[6]) | ((unsigned int)f2b(acc[7]) << 16);
      *((uint4*)out + (size_t)u * HW_ + y * W_ + x) = o;
    }
  }
}

// ---------------- k_attn: MFMA windowed channel attention, V direct-from-global (R7 verbatim) ----------------
#define P1 200   // shorts per px in LDS (q,k only: 192 + 8 pad; 25 uint4)
#define P8 1608  // shorts per row of 8 px (201 uint4 -> bank offset 4 per row: load-bearing)
__global__ __launch_bounds__(192) void k_attn(const unsigned short* __restrict__ qd,
                                              const float* __restrict__ temp,
                                              unsigned short* __restrict__ tout) {
  __shared__ __align__(16) unsigned short flat[8 * P8];    // 25,728 B
  __shared__ __align__(16) unsigned short attnL[3 * 32 * 40];
  __shared__ float invn[3 * 32];
  const int tid = threadIdx.x;
  const int wi = blockIdx.x, t = blockIdx.y;
  const int i0 = (t / 5) * 50, j0 = (t % 5) * 50;
  const int wy = wi >> 3, wx = wi & 7;
  const int gy0 = i0 + wy * 8, gx0 = j0 + wx * 8;

  {  // stage q,k planes (0..23): (u, r, j) -> flat[r][j][u*8]
    const size_t base = (size_t)gy0 * W_ + gx0;
    for (int idx = tid; idx < 24 * 64; idx += 192) {
      int u = idx >> 6, rj = idx & 63, r = rj >> 3, j = rj & 7;
      uint4 v = ((const uint4*)qd)[(size_t)u * HW_ + base + r * W_ + j];
      ((uint4*)flat)[r * 201 + j * 25 + u] = v;
    }
  }
  __syncthreads();

  const int h = tid >> 6, lane = tid & 63;
  const int quad = lane >> 4, lo = lane & 15;
  const int cb = h * 32;

  bf16x8 qf[2][2], kf[2][2];
#pragma unroll
  for (int mt = 0; mt < 2; ++mt)
#pragma unroll
    for (int kt = 0; kt < 2; ++kt) {
      const int rbase = (kt * 4 + quad) * P8;
      const int cq = cb + mt * 16 + lo;
      const int ck = 96 + cb + mt * 16 + lo;
      bf16x8 q8, k8;
#pragma unroll
      for (int j = 0; j < 8; ++j) {
        q8[j] = (short)flat[rbase + j * P1 + cq];
        k8[j] = (short)flat[rbase + j * P1 + ck];
      }
      qf[mt][kt] = q8;
      kf[mt][kt] = k8;
    }

  f32x4 S[2][2];
#pragma unroll
  for (int mt = 0; mt < 2; ++mt)
#pragma unroll
    for (int nt = 0; nt < 2; ++nt) {
      S[mt][nt] = {0.f, 0.f, 0.f, 0.f};
#pragma unroll
      for (int kt = 0; kt < 2; ++kt)
        S[mt][nt] = __builtin_amdgcn_mfma_f32_16x16x32_bf16(qf[mt][kt], kf[nt][kt], S[mt][nt], 0, 0, 0);
    }

  float ivk[2];
#pragma unroll
  for (int mt = 0; mt < 2; ++mt) {
    float sq = 0.f, sk = 0.f;
#pragma unroll
    for (int kt = 0; kt < 2; ++kt)
#pragma unroll
      for (int j = 0; j < 8; ++j) {
        float a = b2f((unsigned short)qf[mt][kt][j]);
        float b = b2f((unsigned short)kf[mt][kt][j]);
        sq += a * a;
        sk += b * b;
      }
    sq += __shfl_xor(sq, 16);
    sq += __shfl_xor(sq, 32);
    sk += __shfl_xor(sk, 16);
    sk += __shfl_xor(sk, 32);
    if (quad == 0) invn[h * 32 + mt * 16 + lo] = 1.f / fmaxf(sqrtf(sq), 1e-12f);
    ivk[mt] = 1.f / fmaxf(sqrtf(sk), 1e-12f);
  }
  __syncthreads();

  const float ts = temp[h];
#pragma unroll
  for (int mt = 0; mt < 2; ++mt)
#pragma unroll
    for (int nt = 0; nt < 2; ++nt)
#pragma unroll
      for (int r = 0; r < 4; ++r) {
        int c = mt * 16 + quad * 4 + r;
        float v = S[mt][nt][r] * invn[h * 32 + c] * ivk[nt] * ts;
        attnL[(h * 32 + c) * 40 + nt * 16 + lo] = f2b(fmaxf(v, 0.f));
      }
  __syncthreads();

  bf16x8 af[2];
#pragma unroll
  for (int mt = 0; mt < 2; ++mt)
    af[mt] = *(const bf16x8*)&attnL[(h * 32 + mt * 16 + lo) * 40 + quad * 8];

  const int uv = 24 + h * 4 + quad;
  f32x4 O[2][4];
#pragma unroll
  for (int nt = 0; nt < 4; ++nt) {
    const int px = nt * 16 + lo;
    const size_t gpx = (size_t)(gy0 + (px >> 3)) * W_ + gx0 + (px & 7);
    uint4 vraw = ((const uint4*)qd)[(size_t)uv * HW_ + gpx];
    bf16x8 vf = *reinterpret_cast<bf16x8*>(&vraw);
#pragma unroll
    for (int mt = 0; mt < 2; ++mt) {
      f32x4 z = {0.f, 0.f, 0.f, 0.f};
      O[mt][nt] = __builtin_amdgcn_mfma_f32_16x16x32_bf16(af[mt], vf, z, 0, 0, 0);
    }
  }
  __syncthreads();

  unsigned short* Cs = flat;  // [64 px][104] overlay
#pragma unroll
  for (int mt = 0; mt < 2; ++mt)
#pragma unroll
    for (int nt = 0; nt < 4; ++nt) {
      const int px = nt * 16 + lo;
      unsigned int p0 = (unsigned int)f2b(O[mt][nt][0]) | ((unsigned int)f2b(O[mt][nt][1]) << 16);
      unsigned int p1 = (unsigned int)f2b(O[mt][nt][2]) | ((unsigned int)f2b(O[mt][nt][3]) << 16);
      *(uint2*)&Cs[px * 104 + cb + mt * 16 + quad * 4] = make_uint2(p0, p1);
    }
  __syncthreads();

  for (int idx = tid; idx < 64 * 12; idx += 192) {
    int rec = idx / 12, u = idx - (idx / 12) * 12;
    int r = rec >> 3, j = rec & 7;
    size_t g = (size_t)t * 4096 + (wy * 8 + r) * 64 + wx * 8 + j;
    ((uint4*)tout)[g * 12 + u] = ((const uint4*)(Cs + rec * 104))[u];
  }
}

// ---------------- k_avgproj v2: per-lane averaged B fragments, A-only LDS ----------------
__global__ __launch_bounds__(256, 4) void k_avgproj(const float* __restrict__ w,
                                                    const unsigned short* __restrict__ tout,
                                                    float* __restrict__ outf) {
  __shared__ __align__(16) unsigned short As[96 * 104];  // 19,968 B
  const int tid = threadIdx.x;
  const int wid = tid >> 6, lane = tid & 63;
  const int quad = lane >> 4, lo = lane & 15;
  const int px0 = blockIdx.x * 64;
  const int px = px0 + wid * 16 + lo;  // always < HW_

  for (int l = tid; l < 96 * 24; l += 256) {
    int o = l / 24, c4 = (l - (l / 24) * 24) * 4;
    float4 v = *(const float4*)&w[o * 96 + c4];
    unsigned int p0 = (unsigned int)f2b(v.x) | ((unsigned int)f2b(v.y) << 16);
    unsigned int p1 = (unsigned int)f2b(v.z) | ((unsigned int)f2b(v.w) << 16);
    *(uint2*)&As[o * 104 + c4] = make_uint2(p0, p1);
  }

  // per-lane averaging of this lane's B-fragment channels: ch = ks*32 + quad*8 + i
  const int y = px / W_, xx = px - y * W_;
  int loy = (y >= 64) ? (y - 14) / 50 : 0;
  int hiy = y / 50; if (hiy > 4) hiy = 4;
  int lox = (xx >= 64) ? (xx - 14) / 50 : 0;
  int hix = xx / 50; if (hix > 4) hix = 4;
  float a24[24];
#pragma unroll
  for (int i = 0; i < 24; ++i) a24[i] = 0.f;
  int cnt = 0;
  for (int ty = loy; ty <= hiy; ++ty)
    for (int tx = lox; tx <= hix; ++tx) {
      size_t rec = (size_t)(ty * 5 + tx) * 4096 + ((y - ty * 50) << 6) + (xx - tx * 50);
      const uint4* rp = (const uint4*)tout + rec * 12 + quad;
#pragma unroll
      for (int ks = 0; ks < 3; ++ks) {
        uint4 v = rp[ks * 4];
        a24[ks * 8 + 0] += lo_f(v.x); a24[ks * 8 + 1] += hi_f(v.x);
        a24[ks * 8 + 2] += lo_f(v.y); a24[ks * 8 + 3] += hi_f(v.y);
        a24[ks * 8 + 4] += lo_f(v.z); a24[ks * 8 + 5] += hi_f(v.z);
        a24[ks * 8 + 6] += lo_f(v.w); a24[ks * 8 + 7] += hi_f(v.w);
      }
      ++cnt;
    }
  const float inv = 1.f / (float)cnt;
  bf16x8 bf[3];
#pragma unroll
  for (int ks = 0; ks < 3; ++ks) {
    union { bf16x8 v; unsigned short s[8]; } u;
#pragma unroll
    for (int i = 0; i < 8; ++i) u.s[i] = f2b(a24[ks * 8 + i] * inv);
    bf[ks] = u.v;
  }
  __syncthreads();

  f32x4 acc[6];
#pragma unroll
  for (int mt = 0; mt < 6; ++mt) acc[mt] = {0.f, 0.f, 0.f, 0.f};
#pragma unroll
  for (int ks = 0; ks < 3; ++ks) {
    const int kb = ks * 32 + quad * 8;
#pragma unroll
    for (int mt = 0; mt < 6; ++mt) {
      bf16x8 a = *(const bf16x8*)&As[(mt * 16 + lo) * 104 + kb];
      acc[mt] = __builtin_amdgcn_mfma_f32_16x16x32_bf16(a, bf[ks], acc[mt], 0, 0, 0);
    }
  }

  {
    int y2 = y + 4; if (y2 >= H_) y2 -= H_;
    int x2 = xx + 4; if (x2 >= W_) x2 -= W_;
    int tp = y2 * W_ + x2;
#pragma unroll
    for (int mt = 0; mt < 6; ++mt) {
      int row = mt * 16 + quad * 4;
#pragma unroll
      for (int r = 0; r < 4; ++r)
        outf[(size_t)(row + r) * HW_ + tp] = acc[mt][r];
    }
  }
}

extern "C" void kernel_launch(void* const* d_in, const int* in_sizes, int n_in,
                              void* d_out, int out_size, void* d_ws, size_t ws_size,
                              hipStream_t stream) {
  (void)in_sizes; (void)n_in; (void)out_size; (void)ws_size;
  const float* x = (const float*)d_in[0];
  const float* temp = (const float*)d_in[1];
  const float* qkvw = (const float*)d_in[2];
  const float* dww = (const float*)d_in[3];
  const float* projw = (const float*)d_in[4];
  float* out = (float*)d_out;

  char* ws = (char*)d_ws;
  const size_t SZQ = (size_t)288 * HW_ * 2;  // 40,144,896 B
  // [0, SZQ):      qkvb planes -> tout records (19.7 MB overlay after k_dw)
  // [SZQ, 2*SZQ):  qkvd planes
  unsigned short* qkvb = (unsigned short*)ws;
  unsigned short* tout = (unsigned short*)ws;
  unsigned short* qkvd = (unsigned short*)(ws + SZQ);

  k_gemm<<<dim3(1089), 256, 0, stream>>>(x, qkvw, qkvb);
  k_dw<<<dim3(5, 17, 36), 256, 0, stream>>>(qkvb, dww, qkvd);
  k_attn<<<dim3(64, 25), 192, 0, stream>>>(qkvd, temp, tout);
  k_avgproj<<<dim3(1089), 256, 0, stream>>>(projw, tout, out);
}